// Round 12
// baseline (262.541 us; speedup 1.0000x reference)
//
#include <hip/hip_runtime.h>

typedef unsigned short u16;
typedef __bf16 bf16x8 __attribute__((ext_vector_type(8)));
typedef float f32x4 __attribute__((ext_vector_type(4)));
typedef short s16x4 __attribute__((ext_vector_type(4)));

#define S_LEN  2048
#define NHEADS 16
#define NKVH   4
#define HDIM   128
#define BB     2
#define MROWS  4096   // B*S
#define QKV_N  3072   // NH*HD + 2*NKV*HD
#define HID    2048

__device__ __forceinline__ u16 f2b(float f) {
  union { float f; unsigned u; } x; x.f = f;
  unsigned r = x.u + 0x7fffu + ((x.u >> 16) & 1u);
  return (u16)(r >> 16);
}
__device__ __forceinline__ float b2f(u16 v) {
  union { unsigned u; float f; } x; x.u = ((unsigned)v) << 16;
  return x.f;
}
__device__ __forceinline__ void gload_lds16(const u16* g, u16* l) {
  __builtin_amdgcn_global_load_lds((__attribute__((address_space(1))) void*)g,
                                   (__attribute__((address_space(3))) void*)l,
                                   16, 0, 0);
}
__device__ __forceinline__ unsigned cvtpk(float lo, float hi) {
  unsigned r;
  asm("v_cvt_pk_bf16_f32 %0, %1, %2" : "=v"(r) : "v"(lo), "v"(hi));
  return r;
}
__device__ __forceinline__ float fexp2(float x) {   // raw v_exp_f32 (2^x)
  float r;
  asm("v_exp_f32 %0, %1" : "=v"(r) : "v"(x));
  return r;
}
#if __has_builtin(__builtin_amdgcn_mfma_f32_16x16x16bf16_1k)
__device__ __forceinline__ f32x4 mfma16(s16x4 a, s16x4 b, f32x4 c) {
  return __builtin_amdgcn_mfma_f32_16x16x16bf16_1k(a, b, c, 0, 0, 0);
}
#else
__device__ __forceinline__ f32x4 mfma16(s16x4 a, s16x4 b, f32x4 c) {
  asm("v_mfma_f32_16x16x16_bf16 %0, %1, %2, %0" : "+v"(c) : "v"(a), "v"(b));
  return c;
}
#endif

#define SBAR() do { __builtin_amdgcn_sched_barrier(0); \
                    __builtin_amdgcn_s_barrier();      \
                    __builtin_amdgcn_sched_barrier(0); } while (0)

// ---- one-launch prep: all fp32->bf16 converts + RoPE cos/sin table ----
#define PB_X   8192
#define PB_WQ  (PB_X + 4096)
#define PB_WK  (PB_WQ + 1024)
#define PB_WV  (PB_WK + 1024)
#define PB_WO  (PB_WV + 4096)
#define PB_CS  (PB_WO + 512)
__global__ void k_prep(const float* __restrict__ x,
                       const float* __restrict__ Wq, const float* __restrict__ Wk,
                       const float* __restrict__ Wv, const float* __restrict__ Wo,
                       u16* __restrict__ xb, u16* __restrict__ Wqkvb,
                       u16* __restrict__ Wob, float* __restrict__ cs)
{
  const int bid = blockIdx.x, tid = threadIdx.x;
  const float* src; u16* dst; int i;
  if (bid < PB_X)       { i = bid * 256 + tid;            src = x;  dst = xb; }
  else if (bid < PB_WQ) { i = (bid - PB_X) * 256 + tid;   src = Wq; dst = Wqkvb; }
  else if (bid < PB_WK) { i = (bid - PB_WQ) * 256 + tid;  src = Wk; dst = Wqkvb + (size_t)2048 * HID; }
  else if (bid < PB_WV) { i = (bid - PB_WK) * 256 + tid;  src = Wv; dst = Wqkvb + (size_t)2560 * HID; }
  else if (bid < PB_WO) { i = (bid - PB_WV) * 256 + tid;  src = Wo; dst = Wob; }
  else {
    const int p = (bid - PB_WO) * 256 + tid;
    const int s = p >> 6, j = p & 63;
    float inv = expf(-(float)j * 0.14391156831212787f);
    float ang = (float)s * inv;
    float c, sn; sincosf(ang, &sn, &c);
    cs[p * 2 + 0] = c; cs[p * 2 + 1] = sn;
    return;
  }
  float4 v = ((const float4*)src)[i];
  ushort4 o;
  o.x = f2b(v.x); o.y = f2b(v.y); o.z = f2b(v.z); o.w = f2b(v.w);
  ((ushort4*)dst)[i] = o;
}

// ======================================================================
// 8-phase-style 256x256 GEMM (T2 swizzle + T3/T4 counted-vmcnt + T5)
// ======================================================================
#define MFMA_GRP(AV, BV, MO, NO)                                              \
  __builtin_amdgcn_s_setprio(1);                                              \
  _Pragma("unroll") for (int kk = 0; kk < 2; ++kk)                            \
  _Pragma("unroll") for (int mm = 0; mm < 4; ++mm)                            \
  _Pragma("unroll") for (int nn = 0; nn < 2; ++nn)                            \
    acc[(MO) + mm][(NO) + nn] = __builtin_amdgcn_mfma_f32_16x16x32_bf16(      \
        AV[kk][mm], BV[kk][nn], acc[(MO) + mm][(NO) + nn], 0, 0, 0);          \
  __builtin_amdgcn_s_setprio(0);

template <int OUT_BF16>
__global__ __launch_bounds__(512, 2) void k_gemm256(
    const u16* __restrict__ A, const u16* __restrict__ Bm, void* __restrict__ Cv,
    int M, int N, int K)
{
  __shared__ u16 AL[2][2][8192];   // 64 KB
  __shared__ u16 BL[2][2][8192];   // 64 KB
  const int tid = threadIdx.x;
  const int wave = tid >> 6, lane = tid & 63;
  const int l15 = lane & 15, l4 = lane >> 4;
  const int wr = wave >> 2, wc = wave & 3;
  const int gx = gridDim.x;
  const int nwg = gx * gridDim.y;
  int bid = blockIdx.y * gx + blockIdx.x;
  bid = (bid & 7) * (nwg >> 3) + (bid >> 3);
  const int col0 = (bid % gx) * 256, row0 = (bid / gx) * 256;

  int srcOff[2], dstD[2];
#pragma unroll
  for (int li = 0; li < 2; ++li) {
    const int D = (li * 512 + tid) * 16;
    const int off_p = D & 1023, si = D >> 10;
    const int off_l = off_p ^ (((off_p >> 9) & 1) << 5);
    const int R = si >> 1, C = si & 1;
    const int row = R * 16 + (off_l >> 6);
    const int colb = C * 64 + (off_l & 63);
    srcOff[li] = row * K + (colb >> 1);
    dstD[li] = D;
  }
  const int laneoff = (l15 * 64 + l4 * 16) ^ ((l15 >> 3) << 5);

  auto stage = [&](const u16* __restrict__ G, int grow0, int kb, u16* lds) {
#pragma unroll
    for (int li = 0; li < 2; ++li)
      gload_lds16(G + (size_t)grow0 * K + kb + srcOff[li],
                  (u16*)((char*)lds + dstD[li]));
  };

  f32x4 acc[8][4];
#pragma unroll
  for (int m = 0; m < 8; ++m)
#pragma unroll
    for (int n = 0; n < 4; ++n) acc[m][n] = f32x4{0.f, 0.f, 0.f, 0.f};

  const int nk = K >> 6;
  stage(A,  row0,       0,  &AL[0][0][0]);
  stage(A,  row0 + 128, 0,  &AL[0][1][0]);
  stage(Bm, col0,       0,  &BL[0][0][0]);
  stage(Bm, col0 + 128, 0,  &BL[0][1][0]);
  stage(A,  row0,       64, &AL[1][0][0]);
  stage(A,  row0 + 128, 64, &AL[1][1][0]);
  asm volatile("s_waitcnt vmcnt(4)" ::: "memory");
  SBAR();

  for (int t = 0; t < nk; ++t) {
    const int bi = t & 1;
    const bool sB = (t + 1 < nk);
    const bool sA = (t + 2 < nk);
    const char* Ab = (const char*)&AL[bi][wr][0];
    const char* Bb = (const char*)&BL[bi][wc >> 1][0] + (wc & 1) * 8192;
    bf16x8 a0[2][4], a1[2][4], b0[2][2], b1[2][2];
#pragma unroll
    for (int kk = 0; kk < 2; ++kk)
#pragma unroll
      for (int m = 0; m < 4; ++m)
        a0[kk][m] = *(const bf16x8*)(Ab + m * 2048 + kk * 1024 + laneoff);
#pragma unroll
    for (int kk = 0; kk < 2; ++kk)
#pragma unroll
      for (int n = 0; n < 2; ++n)
        b0[kk][n] = *(const bf16x8*)(Bb + n * 2048 + kk * 1024 + laneoff);
    if (sB) stage(Bm, col0, (t + 1) * 64, &BL[bi ^ 1][0][0]);
    SBAR();
    MFMA_GRP(a0, b0, 0, 0);
    SBAR();
#pragma unroll
    for (int kk = 0; kk < 2; ++kk)
#pragma unroll
      for (int m = 0; m < 4; ++m)
        a1[kk][m] = *(const bf16x8*)(Ab + (m + 4) * 2048 + kk * 1024 + laneoff);
    if (sB) stage(Bm, col0 + 128, (t + 1) * 64, &BL[bi ^ 1][1][0]);
    SBAR();
    MFMA_GRP(a1, b0, 4, 0);
    SBAR();
#pragma unroll
    for (int kk = 0; kk < 2; ++kk)
#pragma unroll
      for (int n = 0; n < 2; ++n)
        b1[kk][n] = *(const bf16x8*)(Bb + (n + 2) * 2048 + kk * 1024 + laneoff);
    if (sA) stage(A, row0, (t + 2) * 64, &AL[bi][0][0]);
    SBAR();
    MFMA_GRP(a1, b1, 4, 2);
    SBAR();
    if (sA) {
      stage(A, row0 + 128, (t + 2) * 64, &AL[bi][1][0]);
      asm volatile("s_waitcnt vmcnt(4)" ::: "memory");
    } else if (sB) {
      asm volatile("s_waitcnt vmcnt(0)" ::: "memory");
    }
    SBAR();
    MFMA_GRP(a0, b1, 0, 2);
    SBAR();
  }

#pragma unroll
  for (int m = 0; m < 8; ++m) {
    const int r = row0 + wr * 128 + m * 16 + l4 * 4;
#pragma unroll
    for (int n = 0; n < 4; ++n) {
      const int c = col0 + wc * 64 + n * 16 + l15;
#pragma unroll
      for (int j = 0; j < 4; ++j) {
        const float v = acc[m][n][j];
        if (OUT_BF16) ((u16*)Cv)[(size_t)(r + j) * N + c] = f2b(v);
        else          ((float*)Cv)[(size_t)(r + j) * N + c] = v;
      }
    }
  }
}

// C[M][N] = A[M][K] * B[N][K]^T, 128x128 tile, BK=32, 2-phase dbuf.
template <int OUT_BF16>
__global__ __launch_bounds__(256) void k_gemm_bt(
    const u16* __restrict__ A, const u16* __restrict__ Bm, void* __restrict__ Cv,
    int M, int N, int K)
{
  __shared__ u16 Al[2][128 * 32];
  __shared__ u16 Bl[2][128 * 32];
  const int tid = threadIdx.x;
  const int wave = tid >> 6, lane = tid & 63;
  const int l15 = lane & 15, l4 = lane >> 4;
  const int wr = wave >> 1, wc = wave & 1;
  const int row0 = blockIdx.y * 128, col0 = blockIdx.x * 128;

  f32x4 zero = {0.f, 0.f, 0.f, 0.f};
  f32x4 acc[4][4];
#pragma unroll
  for (int m = 0; m < 4; ++m)
#pragma unroll
    for (int n = 0; n < 4; ++n) acc[m][n] = zero;

  const int e0 = lane * 8;
  auto stage = [&](int buf, int kb) {
#pragma unroll
    for (int it = 0; it < 2; ++it) {
      const int chunk = it * 4 + wave;
      const int e = chunk * 512 + e0;
      const int r = e >> 5, c = e & 31;
      gload_lds16(A + (size_t)(row0 + r) * K + kb + c, &Al[buf][chunk * 512]);
      gload_lds16(Bm + (size_t)(col0 + r) * K + kb + c, &Bl[buf][chunk * 512]);
    }
  };

  stage(0, 0);
  asm volatile("s_waitcnt vmcnt(0)" ::: "memory");
  SBAR();
  int cur = 0;
  for (int kb = 0; kb < K; kb += 32) {
    if (kb + 32 < K) stage(cur ^ 1, kb + 32);   // issue early; lands under MFMA
    bf16x8 af[4], bfv[4];
#pragma unroll
    for (int m = 0; m < 4; ++m)
      af[m] = *(const bf16x8*)(&Al[cur][(wr * 64 + m * 16 + l15) * 32 + l4 * 8]);
#pragma unroll
    for (int n = 0; n < 4; ++n)
      bfv[n] = *(const bf16x8*)(&Bl[cur][(wc * 64 + n * 16 + l15) * 32 + l4 * 8]);
    __builtin_amdgcn_s_setprio(1);
#pragma unroll
    for (int m = 0; m < 4; ++m)
#pragma unroll
      for (int n = 0; n < 4; ++n)
        acc[m][n] = __builtin_amdgcn_mfma_f32_16x16x32_bf16(af[m], bfv[n], acc[m][n], 0, 0, 0);
    __builtin_amdgcn_s_setprio(0);
    asm volatile("s_waitcnt vmcnt(0)" ::: "memory");
    SBAR();
    cur ^= 1;
  }
#pragma unroll
  for (int m = 0; m < 4; ++m) {
    const int r = row0 + wr * 64 + m * 16 + l4 * 4;
#pragma unroll
    for (int n = 0; n < 4; ++n) {
      const int c = col0 + wc * 64 + n * 16 + l15;
#pragma unroll
      for (int j = 0; j < 4; ++j) {
        const float v = acc[m][n][j];
        if (OUT_BF16) ((u16*)Cv)[(size_t)(r + j) * N + c] = f2b(v);
        else          ((float*)Cv)[(size_t)(r + j) * N + c] = v;
      }
    }
  }
}

// ---- fused RoPE (Q pre-scaled by scale*log2e) + K RoPE + V transpose ----
__global__ __launch_bounds__(256) void k_ropev(
    const u16* __restrict__ qkv, const float* __restrict__ cs,
    u16* __restrict__ Qr, u16* __restrict__ Kr, u16* __restrict__ Vt)
{
  const int blk = blockIdx.x;
  const int b = blk >> 8, s0 = (blk & 255) << 3;
  const int tid = threadIdx.x;
  const float S2 = 0.08838834764831845f * 1.4426950408889634f;
#pragma unroll
  for (int p = tid; p < 8192; p += 256) {
    const int s = p >> 10, rem = p & 1023, h = rem >> 6, j = rem & 63;
    const int sg = s0 + s;
    const float c = cs[(sg * 64 + j) * 2], sn = cs[(sg * 64 + j) * 2 + 1];
    const u16* src = qkv + (size_t)(b * S_LEN + sg) * QKV_N + h * 128;
    const float x0 = b2f(src[j]), x1 = b2f(src[64 + j]);
    const size_t base = ((size_t)(b * NHEADS + h) * S_LEN + sg) * HDIM;
    Qr[base + j]      = f2b((x0 * c - x1 * sn) * S2);
    Qr[base + 64 + j] = f2b((x1 * c + x0 * sn) * S2);
  }
#pragma unroll
  for (int p = tid; p < 2048; p += 256) {
    const int s = p >> 8, rem = p & 255, h = rem >> 6, j = rem & 63;
    const int sg = s0 + s;
    const float c = cs[(sg * 64 + j) * 2], sn = cs[(sg * 64 + j) * 2 + 1];
    const u16* src = qkv + (size_t)(b * S_LEN + sg) * QKV_N + 2048 + h * 128;
    const float x0 = b2f(src[j]), x1 = b2f(src[64 + j]);
    const size_t base = ((size_t)(b * NKVH + h) * S_LEN + sg) * HDIM;
    Kr[base + j]      = f2b(x0 * c - x1 * sn);
    Kr[base + 64 + j] = f2b(x1 * c + x0 * sn);
  }
#pragma unroll
  for (int vi = 0; vi < 2; ++vi) {
    const int idx = vi * 256 + tid, h = idx >> 7, d = idx & 127;
    union { u16 u[8]; uint4 v; } bb;
#pragma unroll
    for (int s = 0; s < 8; ++s)
      bb.u[s] = qkv[(size_t)(b * S_LEN + s0 + s) * QKV_N + 2560 + idx];
    *(uint4*)(Vt + ((size_t)(b * NKVH + h) * HDIM + d) * S_LEN + s0) = bb.v;
  }
}

// ---- flash attention v11: KV-split (flash-decoding) for balance.
// 768 blocks: [0,512) = heavy qt 8..15 split in 2 kv-halves (partials);
// [512,768) = light qt 0..7 (direct). Greedy HW refill over 512 slots. ----
__global__ __launch_bounds__(256) void k_attn(
    const u16* __restrict__ Q, const u16* __restrict__ Kr,
    const u16* __restrict__ Vt, u16* __restrict__ Out,
    float* __restrict__ Opart, float* __restrict__ Ml)
{
  __shared__ u16 Kl[2][64 * 128];   // 32 KB dbuf, XOR ^((kv&7)<<4)
  __shared__ u16 Vl[2][128 * 64];   // 32 KB dbuf, XOR ^((d&7)<<4)
  const int tid = threadIdx.x;
  const int wave = tid >> 6, lane = tid & 63;
  const int l15 = lane & 15, l4 = lane >> 4;
  const int bid = blockIdx.x;
  // decode: bid&7 -> (b,kvh) (XCD-exact KV L2 slice); heavy-first order.
  int b, kvh, hsub, qt, t0, t1, item;
  if (bid < 512) {
    kvh = bid & 3; b = (bid >> 2) & 1; hsub = (bid >> 3) & 3;
    const int half = (bid >> 5) & 1;
    qt = 15 - (bid >> 6);                 // 15..8, heavy first
    const int mid = qt + 1, ntt = 2 * qt + 2;
    t0 = half ? mid : 0;
    t1 = half ? ntt : mid;
    item = (((b * 16 + kvh * 4 + hsub) << 3) | (qt - 8)) * 2 + half;
  } else {
    const int idx = bid - 512;
    kvh = idx & 3; b = (idx >> 2) & 1; hsub = (idx >> 3) & 3;
    qt = 7 - (idx >> 5);                  // 7..0
    t0 = 0; t1 = 2 * qt + 2;
    item = -1;
  }
  const int h = kvh * 4 + hsub;
  const int bh = b * NHEADS + h;

  const u16* Kg = Kr + (size_t)(b * NKVH + kvh) * S_LEN * HDIM;
  const u16* Vg = Vt + (size_t)(b * NKVH + kvh) * HDIM * S_LEN;

  // pre-swizzled source offsets (rule 21)
  int ko[4], vo[4];
#pragma unroll
  for (int it = 0; it < 4; ++it) {
    const int c = it * 4 + wave;
    const int L = c * 1024 + lane * 16;
    const int r = L >> 8;  const int w2 = (L & 255) ^ ((r & 7) << 4);
    ko[it] = r * HDIM + (w2 >> 1);
    const int d = L >> 7;  const int wv = (L & 127) ^ ((d & 7) << 4);
    vo[it] = d * S_LEN + (wv >> 1);
  }

  const int qw0 = qt * 128 + wave * 32;
  const u16* Qg = Q + ((size_t)bh * S_LEN + qw0) * HDIM;

  bf16x8 qf[2][4];
#pragma unroll
  for (int mq = 0; mq < 2; ++mq)
#pragma unroll
    for (int kc = 0; kc < 4; ++kc)
      qf[mq][kc] = *(const bf16x8*)(Qg + (mq * 16 + l15) * HDIM + kc * 32 + l4 * 8);

  f32x4 zero = {0.f, 0.f, 0.f, 0.f};
  f32x4 oacc[2][8];
#pragma unroll
  for (int mq = 0; mq < 2; ++mq)
#pragma unroll
    for (int i = 0; i < 8; ++i) oacc[mq][i] = zero;
  float m_r[2] = {-1e30f, -1e30f}, l_p[2] = {0.f, 0.f};

  const int qgl = qw0 + l15;               // lane's q-row (mq=0); +16 for mq=1
  int cur = 0;

  // prologue: issue K(t0), V(t0)
#pragma unroll
  for (int it = 0; it < 4; ++it)
    gload_lds16(Kg + (size_t)(t0 * 64) * HDIM + ko[it], &Kl[0][(it * 4 + wave) * 512]);
#pragma unroll
  for (int it = 0; it < 4; ++it)
    gload_lds16(Vg + (size_t)vo[it] + t0 * 64, &Vl[0][(it * 4 + wave) * 512]);

  for (int t = t0; t < t1; ++t) {
    const int kt = t * 64;
    asm volatile("s_waitcnt vmcnt(0)" ::: "memory");
    SBAR();
    const char* Kb = (const char*)(cur ? &Kl[1][0] : &Kl[0][0]);
    const char* Vb = (const char*)(cur ? &Vl[1][0] : &Vl[0][0]);
    // B: S^T = K Q^T
    f32x4 s[2][4];
#pragma unroll
    for (int mq = 0; mq < 2; ++mq)
#pragma unroll
      for (int n = 0; n < 4; ++n) s[mq][n] = zero;
    __builtin_amdgcn_s_setprio(1);
#pragma unroll
    for (int n = 0; n < 4; ++n) {
      const int row = n * 16 + l15;
#pragma unroll
      for (int kc = 0; kc < 4; ++kc) {
        const int ab = (row * 256 + kc * 64 + l4 * 16) ^ ((row & 7) << 4);
        bf16x8 kf = *(const bf16x8*)(Kb + ab);
        s[0][n] = __builtin_amdgcn_mfma_f32_16x16x32_bf16(kf, qf[0][kc], s[0][n], 0, 0, 0);
        s[1][n] = __builtin_amdgcn_mfma_f32_16x16x32_bf16(kf, qf[1][kc], s[1][n], 0, 0, 0);
      }
    }
    __builtin_amdgcn_s_setprio(0);
    // C: issue K(t+1), V(t+1)
    const int hasNext = (t + 1 < t1);
    if (hasNext) {
      const int ktn = kt + 64;
      u16* Kn = cur ? &Kl[0][0] : &Kl[1][0];
      u16* Vn = cur ? &Vl[0][0] : &Vl[1][0];
#pragma unroll
      for (int it = 0; it < 4; ++it)
        gload_lds16(Kg + (size_t)ktn * HDIM + ko[it], Kn + (it * 4 + wave) * 512);
#pragma unroll
      for (int it = 0; it < 4; ++it)
        gload_lds16(Vg + (size_t)vo[it] + ktn, Vn + (it * 4 + wave) * 512);
    }
    // D: (rare) mask in place + per-lane max + defer-max softmax
    if (kt + 63 > qw0) {
#pragma unroll
      for (int mq = 0; mq < 2; ++mq)
#pragma unroll
        for (int n = 0; n < 4; ++n)
#pragma unroll
          for (int j = 0; j < 4; ++j)
            if (kt + n * 16 + l4 * 4 + j > qgl + mq * 16) s[mq][n][j] = -1e30f;
    }
    float pm[2];
#pragma unroll
    for (int mq = 0; mq < 2; ++mq) {
      pm[mq] = s[mq][0][0];
#pragma unroll
      for (int n = 0; n < 4; ++n)
#pragma unroll
        for (int j = 0; j < 4; ++j) pm[mq] = fmaxf(pm[mq], s[mq][n][j]);
    }
    const bool ok = (pm[0] <= m_r[0] + 11.5416f) && (pm[1] <= m_r[1] + 11.5416f);
    if (!__all(ok)) {
#pragma unroll
      for (int mq = 0; mq < 2; ++mq) {
        float pf = fmaxf(pm[mq], __shfl_xor(pm[mq], 16, 64));
        pf = fmaxf(pf, __shfl_xor(pf, 32, 64));
        const float mn = fmaxf(m_r[mq], pf);
        const float sc = fexp2(m_r[mq] - mn);
        m_r[mq] = mn;
        l_p[mq] *= sc;
        float scq[4];
#pragma unroll
        for (int j = 0; j < 4; ++j) scq[j] = __shfl(sc, l4 * 4 + j, 64);
#pragma unroll
        for (int nd = 0; nd < 8; ++nd)
#pragma unroll
          for (int j = 0; j < 4; ++j) oacc[mq][nd][j] *= scq[j];
      }
    }
    union { unsigned u[2]; s16x4 v; } a[2][4];
#pragma unroll
    for (int mq = 0; mq < 2; ++mq)
#pragma unroll
      for (int n = 0; n < 4; ++n) {
        const float p0 = fexp2(s[mq][n][0] - m_r[mq]);
        const float p1 = fexp2(s[mq][n][1] - m_r[mq]);
        const float p2 = fexp2(s[mq][n][2] - m_r[mq]);
        const float p3 = fexp2(s[mq][n][3] - m_r[mq]);
        l_p[mq] += (p0 + p1) + (p2 + p3);
        a[mq][n].u[0] = cvtpk(p0, p1);
        a[mq][n].u[1] = cvtpk(p2, p3);
      }
    // F: O += P V — n outer, vf batched
    __builtin_amdgcn_s_setprio(1);
#pragma unroll
    for (int n = 0; n < 4; ++n) {
      s16x4 vf[8];
#pragma unroll
      for (int nd = 0; nd < 8; ++nd) {
        const int d = nd * 16 + l15;
        vf[nd] = *(const s16x4*)(Vb + ((d * 128 + n * 32 + l4 * 8) ^ ((d & 7) << 4)));
      }
#pragma unroll
      for (int nd = 0; nd < 8; ++nd) {
        oacc[0][nd] = mfma16(a[0][n].v, vf[nd], oacc[0][nd]);
        oacc[1][nd] = mfma16(a[1][n].v, vf[nd], oacc[1][nd]);
      }
    }
    __builtin_amdgcn_s_setprio(0);
    cur ^= 1;
  }

  // ---- epilogue ----
#pragma unroll
  for (int mq = 0; mq < 2; ++mq) {
    float lp = l_p[mq];
    lp += __shfl_xor(lp, 16, 64);
    lp += __shfl_xor(lp, 32, 64);
    const int rloc = wave * 32 + mq * 16;         // qtile-local row base
    if (item >= 0) {
      // partial: write raw O (f32) + per-row m, l
      if (l4 == 0) {
        Ml[((size_t)item * 2 + 0) * 128 + rloc + l15] = m_r[mq];
        Ml[((size_t)item * 2 + 1) * 128 + rloc + l15] = lp;
      }
#pragma unroll
      for (int nd = 0; nd < 8; ++nd)
#pragma unroll
        for (int j = 0; j < 4; ++j)
          Opart[((size_t)item * 128 + rloc + l4 * 4 + j) * 128 + nd * 16 + l15] =
              oacc[mq][nd][j];
    } else {
      float il[4];
#pragma unroll
      for (int j = 0; j < 4; ++j) il[j] = 1.f / __shfl(lp, l4 * 4 + j, 64);
      const size_t obase =
          ((size_t)b * S_LEN + qw0 + mq * 16 + l4 * 4) * HID + h * HDIM;
#pragma unroll
      for (int nd = 0; nd < 8; ++nd)
#pragma unroll
        for (int j = 0; j < 4; ++j)
          Out[obase + (size_t)j * HID + nd * 16 + l15] = f2b(oacc[mq][nd][j] * il[j]);
    }
  }
}

// ---- merge two kv-half partials per heavy qtile ----
__global__ __launch_bounds__(256) void k_merge(
    const float* __restrict__ Opart, const float* __restrict__ Ml,
    u16* __restrict__ Out)
{
  const int mb = blockIdx.x;           // 256 = 32 bh x 8 qidx
  const int bh = mb & 31, qidx = mb >> 5;
  const int b = bh >> 4, h = bh & 15;
  const int qt = qidx + 8;
  const int i0 = ((bh << 3) | qidx) * 2, i1 = i0 + 1;
  const int tid = threadIdx.x;
  const int col = tid & 127;
  for (int r = tid >> 7; r < 128; r += 2) {
    const float m1 = Ml[((size_t)i0 * 2 + 0) * 128 + r];
    const float l1 = Ml[((size_t)i0 * 2 + 1) * 128 + r];
    const float m2 = Ml[((size_t)i1 * 2 + 0) * 128 + r];
    const float l2 = Ml[((size_t)i1 * 2 + 1) * 128 + r];
    const float m = fmaxf(m1, m2);
    const float e1 = fexp2(m1 - m), e2 = fexp2(m2 - m);
    const float il = 1.f / (l1 * e1 + l2 * e2);
    const float o1 = Opart[((size_t)i0 * 128 + r) * 128 + col];
    const float o2 = Opart[((size_t)i1 * 128 + r) * 128 + col];
    Out[((size_t)b * S_LEN + qt * 128 + r) * HID + h * HDIM + col] =
        f2b((o1 * e1 + o2 * e2) * il);
  }
}

extern "C" void kernel_launch(void* const* d_in, const int* in_sizes, int n_in,
                              void* d_out, int out_size, void* d_ws, size_t ws_size,
                              hipStream_t stream)
{
  const float* x  = (const float*)d_in[0];
  const float* Wq = (const float*)d_in[2];
  const float* Wk = (const float*)d_in[3];
  const float* Wv = (const float*)d_in[4];
  const float* Wo = (const float*)d_in[5];
  float* out = (float*)d_out;

  u16* xb    = (u16*)d_ws;
  u16* Wqkvb = xb    + (size_t)MROWS * HID;
  u16* Wob   = Wqkvb + (size_t)QKV_N * HID;
  u16* qkv   = Wob   + (size_t)HID * HID;
  u16* Qr    = qkv   + (size_t)MROWS * QKV_N;
  u16* Kr    = Qr    + (size_t)BB * NHEADS * S_LEN * HDIM;
  u16* Vt    = Kr    + (size_t)BB * NKVH * S_LEN * HDIM;
  u16* attn  = Vt    + (size_t)BB * NKVH * S_LEN * HDIM;
  float* cs  = (float*)(attn + (size_t)MROWS * HID);   // 2048*64*2 f32
  float* Opart = cs + (size_t)2048 * 128;              // 512*128*128 f32
  float* Ml    = Opart + (size_t)512 * 128 * 128;      // 512*2*128 f32

  k_prep<<<dim3(PB_CS), 256, 0, stream>>>(x, Wq, Wk, Wv, Wo, xb, Wqkvb, Wob, cs);
  k_gemm256<1><<<dim3(QKV_N / 256, MROWS / 256), 512, 0, stream>>>(xb, Wqkvb, qkv, MROWS, QKV_N, HID);
  k_ropev<<<dim3(BB * 256), 256, 0, stream>>>(qkv, cs, Qr, Kr, Vt);
  k_attn<<<dim3(768), 256, 0, stream>>>(Qr, Kr, Vt, attn, Opart, Ml);
  k_merge<<<dim3(256), 256, 0, stream>>>(Opart, Ml, attn);
  k_gemm_bt<0><<<dim3(HID / 128, MROWS / 128), 256, 0, stream>>>(attn, Wob, out, MROWS, HID, HID);
}

// Round 13
// 227.619 us; speedup vs baseline: 1.1534x; 1.1534x over previous
//
#include <hip/hip_runtime.h>

typedef unsigned short u16;
typedef __bf16 bf16x8 __attribute__((ext_vector_type(8)));
typedef float f32x4 __attribute__((ext_vector_type(4)));
typedef short s16x4 __attribute__((ext_vector_type(4)));

#define S_LEN  2048
#define NHEADS 16
#define NKVH   4
#define HDIM   128
#define BB     2
#define MROWS  4096   // B*S
#define QKV_N  3072   // NH*HD + 2*NKV*HD
#define HID    2048

__device__ __forceinline__ u16 f2b(float f) {
  union { float f; unsigned u; } x; x.f = f;
  unsigned r = x.u + 0x7fffu + ((x.u >> 16) & 1u);
  return (u16)(r >> 16);
}
__device__ __forceinline__ float b2f(u16 v) {
  union { unsigned u; float f; } x; x.u = ((unsigned)v) << 16;
  return x.f;
}
__device__ __forceinline__ void gload_lds16(const u16* g, u16* l) {
  __builtin_amdgcn_global_load_lds((__attribute__((address_space(1))) void*)g,
                                   (__attribute__((address_space(3))) void*)l,
                                   16, 0, 0);
}
__device__ __forceinline__ unsigned cvtpk(float lo, float hi) {
  unsigned r;
  asm("v_cvt_pk_bf16_f32 %0, %1, %2" : "=v"(r) : "v"(lo), "v"(hi));
  return r;
}
__device__ __forceinline__ float fexp2(float x) {   // raw v_exp_f32 (2^x)
  float r;
  asm("v_exp_f32 %0, %1" : "=v"(r) : "v"(x));
  return r;
}
#if __has_builtin(__builtin_amdgcn_mfma_f32_16x16x16bf16_1k)
__device__ __forceinline__ f32x4 mfma16(s16x4 a, s16x4 b, f32x4 c) {
  return __builtin_amdgcn_mfma_f32_16x16x16bf16_1k(a, b, c, 0, 0, 0);
}
#else
__device__ __forceinline__ f32x4 mfma16(s16x4 a, s16x4 b, f32x4 c) {
  asm("v_mfma_f32_16x16x16_bf16 %0, %1, %2, %0" : "+v"(c) : "v"(a), "v"(b));
  return c;
}
#endif

#define SBAR() do { __builtin_amdgcn_sched_barrier(0); \
                    __builtin_amdgcn_s_barrier();      \
                    __builtin_amdgcn_sched_barrier(0); } while (0)

// ---- one-launch prep: all fp32->bf16 converts + RoPE cos/sin table ----
#define PB_X   8192
#define PB_WQ  (PB_X + 4096)
#define PB_WK  (PB_WQ + 1024)
#define PB_WV  (PB_WK + 1024)
#define PB_WO  (PB_WV + 4096)
#define PB_CS  (PB_WO + 512)
__global__ void k_prep(const float* __restrict__ x,
                       const float* __restrict__ Wq, const float* __restrict__ Wk,
                       const float* __restrict__ Wv, const float* __restrict__ Wo,
                       u16* __restrict__ xb, u16* __restrict__ Wqkvb,
                       u16* __restrict__ Wob, float* __restrict__ cs)
{
  const int bid = blockIdx.x, tid = threadIdx.x;
  const float* src; u16* dst; int i;
  if (bid < PB_X)       { i = bid * 256 + tid;            src = x;  dst = xb; }
  else if (bid < PB_WQ) { i = (bid - PB_X) * 256 + tid;   src = Wq; dst = Wqkvb; }
  else if (bid < PB_WK) { i = (bid - PB_WQ) * 256 + tid;  src = Wk; dst = Wqkvb + (size_t)2048 * HID; }
  else if (bid < PB_WV) { i = (bid - PB_WK) * 256 + tid;  src = Wv; dst = Wqkvb + (size_t)2560 * HID; }
  else if (bid < PB_WO) { i = (bid - PB_WV) * 256 + tid;  src = Wo; dst = Wob; }
  else {
    const int p = (bid - PB_WO) * 256 + tid;
    const int s = p >> 6, j = p & 63;
    float inv = expf(-(float)j * 0.14391156831212787f);
    float ang = (float)s * inv;
    float c, sn; sincosf(ang, &sn, &c);
    cs[p * 2 + 0] = c; cs[p * 2 + 1] = sn;
    return;
  }
  float4 v = ((const float4*)src)[i];
  ushort4 o;
  o.x = f2b(v.x); o.y = f2b(v.y); o.z = f2b(v.z); o.w = f2b(v.w);
  ((ushort4*)dst)[i] = o;
}

// ======================================================================
// 8-phase-style 256x256 GEMM (T2 swizzle + T3/T4 counted-vmcnt + T5)
// ======================================================================
#define MFMA_GRP(AV, BV, MO, NO)                                              \
  __builtin_amdgcn_s_setprio(1);                                              \
  _Pragma("unroll") for (int kk = 0; kk < 2; ++kk)                            \
  _Pragma("unroll") for (int mm = 0; mm < 4; ++mm)                            \
  _Pragma("unroll") for (int nn = 0; nn < 2; ++nn)                            \
    acc[(MO) + mm][(NO) + nn] = __builtin_amdgcn_mfma_f32_16x16x32_bf16(      \
        AV[kk][mm], BV[kk][nn], acc[(MO) + mm][(NO) + nn], 0, 0, 0);          \
  __builtin_amdgcn_s_setprio(0);

template <int OUT_BF16>
__global__ __launch_bounds__(512, 2) void k_gemm256(
    const u16* __restrict__ A, const u16* __restrict__ Bm, void* __restrict__ Cv,
    int M, int N, int K)
{
  __shared__ u16 AL[2][2][8192];   // 64 KB
  __shared__ u16 BL[2][2][8192];   // 64 KB
  const int tid = threadIdx.x;
  const int wave = tid >> 6, lane = tid & 63;
  const int l15 = lane & 15, l4 = lane >> 4;
  const int wr = wave >> 2, wc = wave & 3;
  const int gx = gridDim.x;
  const int nwg = gx * gridDim.y;
  int bid = blockIdx.y * gx + blockIdx.x;
  bid = (bid & 7) * (nwg >> 3) + (bid >> 3);
  const int col0 = (bid % gx) * 256, row0 = (bid / gx) * 256;

  int srcOff[2], dstD[2];
#pragma unroll
  for (int li = 0; li < 2; ++li) {
    const int D = (li * 512 + tid) * 16;
    const int off_p = D & 1023, si = D >> 10;
    const int off_l = off_p ^ (((off_p >> 9) & 1) << 5);
    const int R = si >> 1, C = si & 1;
    const int row = R * 16 + (off_l >> 6);
    const int colb = C * 64 + (off_l & 63);
    srcOff[li] = row * K + (colb >> 1);
    dstD[li] = D;
  }
  const int laneoff = (l15 * 64 + l4 * 16) ^ ((l15 >> 3) << 5);

  auto stage = [&](const u16* __restrict__ G, int grow0, int kb, u16* lds) {
#pragma unroll
    for (int li = 0; li < 2; ++li)
      gload_lds16(G + (size_t)grow0 * K + kb + srcOff[li],
                  (u16*)((char*)lds + dstD[li]));
  };

  f32x4 acc[8][4];
#pragma unroll
  for (int m = 0; m < 8; ++m)
#pragma unroll
    for (int n = 0; n < 4; ++n) acc[m][n] = f32x4{0.f, 0.f, 0.f, 0.f};

  const int nk = K >> 6;
  stage(A,  row0,       0,  &AL[0][0][0]);
  stage(A,  row0 + 128, 0,  &AL[0][1][0]);
  stage(Bm, col0,       0,  &BL[0][0][0]);
  stage(Bm, col0 + 128, 0,  &BL[0][1][0]);
  stage(A,  row0,       64, &AL[1][0][0]);
  stage(A,  row0 + 128, 64, &AL[1][1][0]);
  asm volatile("s_waitcnt vmcnt(4)" ::: "memory");
  SBAR();

  for (int t = 0; t < nk; ++t) {
    const int bi = t & 1;
    const bool sB = (t + 1 < nk);
    const bool sA = (t + 2 < nk);
    const char* Ab = (const char*)&AL[bi][wr][0];
    const char* Bb = (const char*)&BL[bi][wc >> 1][0] + (wc & 1) * 8192;
    bf16x8 a0[2][4], a1[2][4], b0[2][2], b1[2][2];
#pragma unroll
    for (int kk = 0; kk < 2; ++kk)
#pragma unroll
      for (int m = 0; m < 4; ++m)
        a0[kk][m] = *(const bf16x8*)(Ab + m * 2048 + kk * 1024 + laneoff);
#pragma unroll
    for (int kk = 0; kk < 2; ++kk)
#pragma unroll
      for (int n = 0; n < 2; ++n)
        b0[kk][n] = *(const bf16x8*)(Bb + n * 2048 + kk * 1024 + laneoff);
    if (sB) stage(Bm, col0, (t + 1) * 64, &BL[bi ^ 1][0][0]);
    SBAR();
    MFMA_GRP(a0, b0, 0, 0);
    SBAR();
#pragma unroll
    for (int kk = 0; kk < 2; ++kk)
#pragma unroll
      for (int m = 0; m < 4; ++m)
        a1[kk][m] = *(const bf16x8*)(Ab + (m + 4) * 2048 + kk * 1024 + laneoff);
    if (sB) stage(Bm, col0 + 128, (t + 1) * 64, &BL[bi ^ 1][1][0]);
    SBAR();
    MFMA_GRP(a1, b0, 4, 0);
    SBAR();
#pragma unroll
    for (int kk = 0; kk < 2; ++kk)
#pragma unroll
      for (int n = 0; n < 2; ++n)
        b1[kk][n] = *(const bf16x8*)(Bb + (n + 2) * 2048 + kk * 1024 + laneoff);
    if (sA) stage(A, row0, (t + 2) * 64, &AL[bi][0][0]);
    SBAR();
    MFMA_GRP(a1, b1, 4, 2);
    SBAR();
    if (sA) {
      stage(A, row0 + 128, (t + 2) * 64, &AL[bi][1][0]);
      asm volatile("s_waitcnt vmcnt(4)" ::: "memory");
    } else if (sB) {
      asm volatile("s_waitcnt vmcnt(0)" ::: "memory");
    }
    SBAR();
    MFMA_GRP(a0, b1, 0, 2);
    SBAR();
  }

#pragma unroll
  for (int m = 0; m < 8; ++m) {
    const int r = row0 + wr * 128 + m * 16 + l4 * 4;
#pragma unroll
    for (int n = 0; n < 4; ++n) {
      const int c = col0 + wc * 64 + n * 16 + l15;
#pragma unroll
      for (int j = 0; j < 4; ++j) {
        const float v = acc[m][n][j];
        if (OUT_BF16) ((u16*)Cv)[(size_t)(r + j) * N + c] = f2b(v);
        else          ((float*)Cv)[(size_t)(r + j) * N + c] = v;
      }
    }
  }
}

// C[M][N] = A[M][K] * B[N][K]^T, 128x128 tile, BK=32, 2-phase dbuf.
template <int OUT_BF16>
__global__ __launch_bounds__(256) void k_gemm_bt(
    const u16* __restrict__ A, const u16* __restrict__ Bm, void* __restrict__ Cv,
    int M, int N, int K)
{
  __shared__ u16 Al[2][128 * 32];
  __shared__ u16 Bl[2][128 * 32];
  const int tid = threadIdx.x;
  const int wave = tid >> 6, lane = tid & 63;
  const int l15 = lane & 15, l4 = lane >> 4;
  const int wr = wave >> 1, wc = wave & 1;
  const int row0 = blockIdx.y * 128, col0 = blockIdx.x * 128;

  f32x4 zero = {0.f, 0.f, 0.f, 0.f};
  f32x4 acc[4][4];
#pragma unroll
  for (int m = 0; m < 4; ++m)
#pragma unroll
    for (int n = 0; n < 4; ++n) acc[m][n] = zero;

  const int e0 = lane * 8;
  auto stage = [&](int buf, int kb) {
#pragma unroll
    for (int it = 0; it < 2; ++it) {
      const int chunk = it * 4 + wave;
      const int e = chunk * 512 + e0;
      const int r = e >> 5, c = e & 31;
      gload_lds16(A + (size_t)(row0 + r) * K + kb + c, &Al[buf][chunk * 512]);
      gload_lds16(Bm + (size_t)(col0 + r) * K + kb + c, &Bl[buf][chunk * 512]);
    }
  };

  stage(0, 0);
  asm volatile("s_waitcnt vmcnt(0)" ::: "memory");
  SBAR();
  int cur = 0;
  for (int kb = 0; kb < K; kb += 32) {
    if (kb + 32 < K) stage(cur ^ 1, kb + 32);   // issue early; lands under MFMA
    bf16x8 af[4], bfv[4];
#pragma unroll
    for (int m = 0; m < 4; ++m)
      af[m] = *(const bf16x8*)(&Al[cur][(wr * 64 + m * 16 + l15) * 32 + l4 * 8]);
#pragma unroll
    for (int n = 0; n < 4; ++n)
      bfv[n] = *(const bf16x8*)(&Bl[cur][(wc * 64 + n * 16 + l15) * 32 + l4 * 8]);
    __builtin_amdgcn_s_setprio(1);
#pragma unroll
    for (int m = 0; m < 4; ++m)
#pragma unroll
      for (int n = 0; n < 4; ++n)
        acc[m][n] = __builtin_amdgcn_mfma_f32_16x16x32_bf16(af[m], bfv[n], acc[m][n], 0, 0, 0);
    __builtin_amdgcn_s_setprio(0);
    asm volatile("s_waitcnt vmcnt(0)" ::: "memory");
    SBAR();
    cur ^= 1;
  }
#pragma unroll
  for (int m = 0; m < 4; ++m) {
    const int r = row0 + wr * 64 + m * 16 + l4 * 4;
#pragma unroll
    for (int n = 0; n < 4; ++n) {
      const int c = col0 + wc * 64 + n * 16 + l15;
#pragma unroll
      for (int j = 0; j < 4; ++j) {
        const float v = acc[m][n][j];
        if (OUT_BF16) ((u16*)Cv)[(size_t)(r + j) * N + c] = f2b(v);
        else          ((float*)Cv)[(size_t)(r + j) * N + c] = v;
      }
    }
  }
}

// ---- fused RoPE (Q pre-scaled by scale*log2e) + K RoPE + V transpose ----
__global__ __launch_bounds__(256) void k_ropev(
    const u16* __restrict__ qkv, const float* __restrict__ cs,
    u16* __restrict__ Qr, u16* __restrict__ Kr, u16* __restrict__ Vt)
{
  const int blk = blockIdx.x;
  const int b = blk >> 8, s0 = (blk & 255) << 3;
  const int tid = threadIdx.x;
  const float S2 = 0.08838834764831845f * 1.4426950408889634f;
#pragma unroll
  for (int p = tid; p < 8192; p += 256) {
    const int s = p >> 10, rem = p & 1023, h = rem >> 6, j = rem & 63;
    const int sg = s0 + s;
    const float c = cs[(sg * 64 + j) * 2], sn = cs[(sg * 64 + j) * 2 + 1];
    const u16* src = qkv + (size_t)(b * S_LEN + sg) * QKV_N + h * 128;
    const float x0 = b2f(src[j]), x1 = b2f(src[64 + j]);
    const size_t base = ((size_t)(b * NHEADS + h) * S_LEN + sg) * HDIM;
    Qr[base + j]      = f2b((x0 * c - x1 * sn) * S2);
    Qr[base + 64 + j] = f2b((x1 * c + x0 * sn) * S2);
  }
#pragma unroll
  for (int p = tid; p < 2048; p += 256) {
    const int s = p >> 8, rem = p & 255, h = rem >> 6, j = rem & 63;
    const int sg = s0 + s;
    const float c = cs[(sg * 64 + j) * 2], sn = cs[(sg * 64 + j) * 2 + 1];
    const u16* src = qkv + (size_t)(b * S_LEN + sg) * QKV_N + 2048 + h * 128;
    const float x0 = b2f(src[j]), x1 = b2f(src[64 + j]);
    const size_t base = ((size_t)(b * NKVH + h) * S_LEN + sg) * HDIM;
    Kr[base + j]      = f2b(x0 * c - x1 * sn);
    Kr[base + 64 + j] = f2b(x1 * c + x0 * sn);
  }
#pragma unroll
  for (int vi = 0; vi < 2; ++vi) {
    const int idx = vi * 256 + tid, h = idx >> 7, d = idx & 127;
    union { u16 u[8]; uint4 v; } bb;
#pragma unroll
    for (int s = 0; s < 8; ++s)
      bb.u[s] = qkv[(size_t)(b * S_LEN + s0 + s) * QKV_N + 2560 + idx];
    *(uint4*)(Vt + ((size_t)(b * NKVH + h) * HDIM + d) * S_LEN + s0) = bb.v;
  }
}

// ---- flash attention v13: TWIN-PAIRED grid. Co-resident blocks (c, c+256)
// differ only in bid bit 8 = head bit -> same (b,kvh), same qt (identical
// size, fully dual-resident) and same KV stream (L2-shared). No split,
// no partials, no merge. Single barrier per KV tile; in-reg P; fast exp2. ----
__global__ __launch_bounds__(256) void k_attn(
    const u16* __restrict__ Q, const u16* __restrict__ Kr,
    const u16* __restrict__ Vt, u16* __restrict__ Out)
{
  __shared__ u16 Kl[2][64 * 128];   // 32 KB dbuf, XOR ^((kv&7)<<4)
  __shared__ u16 Vl[2][128 * 64];   // 32 KB dbuf, XOR ^((d&7)<<4)
  const int tid = threadIdx.x;
  const int wave = tid >> 6, lane = tid & 63;
  const int l15 = lane & 15, l4 = lane >> 4;
  const int bid = blockIdx.x;
  // bit layout: [8]=head-hi | [7:4]=qt index | [3]=head-lo | [2:0]=xcd(b,kvh)
  const int xg = bid & 7;
  const int b = xg >> 2, kvh = xg & 3;
  const int h = kvh * 4 + ((bid >> 8) & 1) * 2 + ((bid >> 3) & 1);
  const int qt = 15 - ((bid >> 4) & 15);    // heavy first
  const int bh = b * NHEADS + h;

  const u16* Kg = Kr + (size_t)(b * NKVH + kvh) * S_LEN * HDIM;
  const u16* Vg = Vt + (size_t)(b * NKVH + kvh) * HDIM * S_LEN;

  // pre-swizzled source offsets (rule 21)
  int ko[4], vo[4];
#pragma unroll
  for (int it = 0; it < 4; ++it) {
    const int c = it * 4 + wave;
    const int L = c * 1024 + lane * 16;
    const int r = L >> 8;  const int w2 = (L & 255) ^ ((r & 7) << 4);
    ko[it] = r * HDIM + (w2 >> 1);
    const int d = L >> 7;  const int wv = (L & 127) ^ ((d & 7) << 4);
    vo[it] = d * S_LEN + (wv >> 1);
  }

  const int qw0 = qt * 128 + wave * 32;
  const u16* Qg = Q + ((size_t)bh * S_LEN + qw0) * HDIM;

  bf16x8 qf[2][4];
#pragma unroll
  for (int mq = 0; mq < 2; ++mq)
#pragma unroll
    for (int kc = 0; kc < 4; ++kc)
      qf[mq][kc] = *(const bf16x8*)(Qg + (mq * 16 + l15) * HDIM + kc * 32 + l4 * 8);

  f32x4 zero = {0.f, 0.f, 0.f, 0.f};
  f32x4 oacc[2][8];
#pragma unroll
  for (int mq = 0; mq < 2; ++mq)
#pragma unroll
    for (int i = 0; i < 8; ++i) oacc[mq][i] = zero;
  float m_r[2] = {-1e30f, -1e30f}, l_p[2] = {0.f, 0.f};

  const int nt = 2 * qt + 2;
  const int qgl = qw0 + l15;               // lane's q-row (mq=0); +16 for mq=1
  int cur = 0;

  // prologue: issue K(0), V(0)
#pragma unroll
  for (int it = 0; it < 4; ++it)
    gload_lds16(Kg + ko[it], &Kl[0][(it * 4 + wave) * 512]);
#pragma unroll
  for (int it = 0; it < 4; ++it)
    gload_lds16(Vg + (size_t)vo[it], &Vl[0][(it * 4 + wave) * 512]);

  for (int t = 0; t < nt; ++t) {
    const int kt = t * 64;
    // A: wait own K(t)+V(t) loads, publish via barrier.
    asm volatile("s_waitcnt vmcnt(0)" ::: "memory");
    SBAR();
    const char* Kb = (const char*)(cur ? &Kl[1][0] : &Kl[0][0]);
    const char* Vb = (const char*)(cur ? &Vl[1][0] : &Vl[0][0]);
    // B: S^T = K Q^T — each kf feeds both q-subtiles
    f32x4 s[2][4];
#pragma unroll
    for (int mq = 0; mq < 2; ++mq)
#pragma unroll
      for (int n = 0; n < 4; ++n) s[mq][n] = zero;
    __builtin_amdgcn_s_setprio(1);
#pragma unroll
    for (int n = 0; n < 4; ++n) {
      const int row = n * 16 + l15;
#pragma unroll
      for (int kc = 0; kc < 4; ++kc) {
        const int ab = (row * 256 + kc * 64 + l4 * 16) ^ ((row & 7) << 4);
        bf16x8 kf = *(const bf16x8*)(Kb + ab);
        s[0][n] = __builtin_amdgcn_mfma_f32_16x16x32_bf16(kf, qf[0][kc], s[0][n], 0, 0, 0);
        s[1][n] = __builtin_amdgcn_mfma_f32_16x16x32_bf16(kf, qf[1][kc], s[1][n], 0, 0, 0);
      }
    }
    __builtin_amdgcn_s_setprio(0);
    // C: issue K(t+1), V(t+1) into the other buffers
    const int hasNext = (t + 1 < nt);
    if (hasNext) {
      const int ktn = kt + 64;
      u16* Kn = cur ? &Kl[0][0] : &Kl[1][0];
      u16* Vn = cur ? &Vl[0][0] : &Vl[1][0];
#pragma unroll
      for (int it = 0; it < 4; ++it)
        gload_lds16(Kg + (size_t)ktn * HDIM + ko[it], Kn + (it * 4 + wave) * 512);
#pragma unroll
      for (int it = 0; it < 4; ++it)
        gload_lds16(Vg + (size_t)vo[it] + ktn, Vn + (it * 4 + wave) * 512);
    }
    // D: (rare) mask in place + per-lane max + defer-max softmax
    if (kt + 63 > qw0) {
#pragma unroll
      for (int mq = 0; mq < 2; ++mq)
#pragma unroll
        for (int n = 0; n < 4; ++n)
#pragma unroll
          for (int j = 0; j < 4; ++j)
            if (kt + n * 16 + l4 * 4 + j > qgl + mq * 16) s[mq][n][j] = -1e30f;
    }
    float pm[2];
#pragma unroll
    for (int mq = 0; mq < 2; ++mq) {
      pm[mq] = s[mq][0][0];
#pragma unroll
      for (int n = 0; n < 4; ++n)
#pragma unroll
        for (int j = 0; j < 4; ++j) pm[mq] = fmaxf(pm[mq], s[mq][n][j]);
    }
    const bool ok = (pm[0] <= m_r[0] + 11.5416f) && (pm[1] <= m_r[1] + 11.5416f);
    if (!__all(ok)) {
#pragma unroll
      for (int mq = 0; mq < 2; ++mq) {
        float pf = fmaxf(pm[mq], __shfl_xor(pm[mq], 16, 64));
        pf = fmaxf(pf, __shfl_xor(pf, 32, 64));
        const float mn = fmaxf(m_r[mq], pf);
        const float sc = fexp2(m_r[mq] - mn);
        m_r[mq] = mn;
        l_p[mq] *= sc;
        float scq[4];
#pragma unroll
        for (int j = 0; j < 4; ++j) scq[j] = __shfl(sc, l4 * 4 + j, 64);
#pragma unroll
        for (int nd = 0; nd < 8; ++nd)
#pragma unroll
          for (int j = 0; j < 4; ++j) oacc[mq][nd][j] *= scq[j];
      }
    }
    union { unsigned u[2]; s16x4 v; } a[2][4];
#pragma unroll
    for (int mq = 0; mq < 2; ++mq)
#pragma unroll
      for (int n = 0; n < 4; ++n) {
        const float p0 = fexp2(s[mq][n][0] - m_r[mq]);
        const float p1 = fexp2(s[mq][n][1] - m_r[mq]);
        const float p2 = fexp2(s[mq][n][2] - m_r[mq]);
        const float p3 = fexp2(s[mq][n][3] - m_r[mq]);
        l_p[mq] += (p0 + p1) + (p2 + p3);
        a[mq][n].u[0] = cvtpk(p0, p1);
        a[mq][n].u[1] = cvtpk(p2, p3);
      }
    // F: O += P V — n outer, vf batched 8-at-a-time
    __builtin_amdgcn_s_setprio(1);
#pragma unroll
    for (int n = 0; n < 4; ++n) {
      s16x4 vf[8];
#pragma unroll
      for (int nd = 0; nd < 8; ++nd) {
        const int d = nd * 16 + l15;
        vf[nd] = *(const s16x4*)(Vb + ((d * 128 + n * 32 + l4 * 8) ^ ((d & 7) << 4)));
      }
#pragma unroll
      for (int nd = 0; nd < 8; ++nd) {
        oacc[0][nd] = mfma16(a[0][n].v, vf[nd], oacc[0][nd]);
        oacc[1][nd] = mfma16(a[1][n].v, vf[nd], oacc[1][nd]);
      }
    }
    __builtin_amdgcn_s_setprio(0);
    cur ^= 1;
  }

  // ---- epilogue ----
#pragma unroll
  for (int mq = 0; mq < 2; ++mq) {
    float lp = l_p[mq];
    lp += __shfl_xor(lp, 16, 64);
    lp += __shfl_xor(lp, 32, 64);
    float il[4];
#pragma unroll
    for (int j = 0; j < 4; ++j) il[j] = 1.f / __shfl(lp, l4 * 4 + j, 64);
    const size_t obase =
        ((size_t)b * S_LEN + qw0 + mq * 16 + l4 * 4) * HID + h * HDIM;
#pragma unroll
    for (int nd = 0; nd < 8; ++nd)
#pragma unroll
      for (int j = 0; j < 4; ++j)
        Out[obase + (size_t)j * HID + nd * 16 + l15] = f2b(oacc[mq][nd][j] * il[j]);
  }
}

extern "C" void kernel_launch(void* const* d_in, const int* in_sizes, int n_in,
                              void* d_out, int out_size, void* d_ws, size_t ws_size,
                              hipStream_t stream)
{
  const float* x  = (const float*)d_in[0];
  const float* Wq = (const float*)d_in[2];
  const float* Wk = (const float*)d_in[3];
  const float* Wv = (const float*)d_in[4];
  const float* Wo = (const float*)d_in[5];
  float* out = (float*)d_out;

  u16* xb    = (u16*)d_ws;
  u16* Wqkvb = xb    + (size_t)MROWS * HID;
  u16* Wob   = Wqkvb + (size_t)QKV_N * HID;
  u16* qkv   = Wob   + (size_t)HID * HID;
  u16* Qr    = qkv   + (size_t)MROWS * QKV_N;
  u16* Kr    = Qr    + (size_t)BB * NHEADS * S_LEN * HDIM;
  u16* Vt    = Kr    + (size_t)BB * NKVH * S_LEN * HDIM;
  u16* attn  = Vt    + (size_t)BB * NKVH * S_LEN * HDIM;
  float* cs  = (float*)(attn + (size_t)MROWS * HID);

  k_prep<<<dim3(PB_CS), 256, 0, stream>>>(x, Wq, Wk, Wv, Wo, xb, Wqkvb, Wob, cs);
  k_gemm256<1><<<dim3(QKV_N / 256, MROWS / 256), 512, 0, stream>>>(xb, Wqkvb, qkv, MROWS, QKV_N, HID);
  k_ropev<<<dim3(BB * 256), 256, 0, stream>>>(qkv, cs, Qr, Kr, Vt);
  k_attn<<<dim3(512), 256, 0, stream>>>(Qr, Kr, Vt, attn);
  k_gemm_bt<0><<<dim3(HID / 128, MROWS / 128), 256, 0, stream>>>(attn, Wob, out, MROWS, HID, HID);
}

// Round 14
// 208.573 us; speedup vs baseline: 1.2587x; 1.0913x over previous
//
#include <hip/hip_runtime.h>

typedef unsigned short u16;
typedef __bf16 bf16x8 __attribute__((ext_vector_type(8)));
typedef float f32x4 __attribute__((ext_vector_type(4)));
typedef short s16x4 __attribute__((ext_vector_type(4)));

#define S_LEN  2048
#define NHEADS 16
#define NKVH   4
#define HDIM   128
#define BB     2
#define MROWS  4096   // B*S
#define QKV_N  3072   // NH*HD + 2*NKV*HD
#define HID    2048

__device__ __forceinline__ u16 f2b(float f) {
  union { float f; unsigned u; } x; x.f = f;
  unsigned r = x.u + 0x7fffu + ((x.u >> 16) & 1u);
  return (u16)(r >> 16);
}
__device__ __forceinline__ float b2f(u16 v) {
  union { unsigned u; float f; } x; x.u = ((unsigned)v) << 16;
  return x.f;
}
__device__ __forceinline__ void gload_lds16(const u16* g, u16* l) {
  __builtin_amdgcn_global_load_lds((__attribute__((address_space(1))) void*)g,
                                   (__attribute__((address_space(3))) void*)l,
                                   16, 0, 0);
}
__device__ __forceinline__ unsigned cvtpk(float lo, float hi) {
  unsigned r;
  asm("v_cvt_pk_bf16_f32 %0, %1, %2" : "=v"(r) : "v"(lo), "v"(hi));
  return r;
}
#if __has_builtin(__builtin_amdgcn_mfma_f32_16x16x16bf16_1k)
__device__ __forceinline__ f32x4 mfma16(s16x4 a, s16x4 b, f32x4 c) {
  return __builtin_amdgcn_mfma_f32_16x16x16bf16_1k(a, b, c, 0, 0, 0);
}
#else
__device__ __forceinline__ f32x4 mfma16(s16x4 a, s16x4 b, f32x4 c) {
  asm("v_mfma_f32_16x16x16_bf16 %0, %1, %2, %0" : "+v"(c) : "v"(a), "v"(b));
  return c;
}
#endif

#define SBAR() do { __builtin_amdgcn_sched_barrier(0); \
                    __builtin_amdgcn_s_barrier();      \
                    __builtin_amdgcn_sched_barrier(0); } while (0)

// ---- one-launch prep: all fp32->bf16 converts + RoPE cos/sin table ----
#define PB_X   8192
#define PB_WQ  (PB_X + 4096)
#define PB_WK  (PB_WQ + 1024)
#define PB_WV  (PB_WK + 1024)
#define PB_WO  (PB_WV + 4096)
#define PB_CS  (PB_WO + 512)
__global__ void k_prep(const float* __restrict__ x,
                       const float* __restrict__ Wq, const float* __restrict__ Wk,
                       const float* __restrict__ Wv, const float* __restrict__ Wo,
                       u16* __restrict__ xb, u16* __restrict__ Wqkvb,
                       u16* __restrict__ Wob, float* __restrict__ cs)
{
  const int bid = blockIdx.x, tid = threadIdx.x;
  const float* src; u16* dst; int i;
  if (bid < PB_X)       { i = bid * 256 + tid;            src = x;  dst = xb; }
  else if (bid < PB_WQ) { i = (bid - PB_X) * 256 + tid;   src = Wq; dst = Wqkvb; }
  else if (bid < PB_WK) { i = (bid - PB_WQ) * 256 + tid;  src = Wk; dst = Wqkvb + (size_t)2048 * HID; }
  else if (bid < PB_WV) { i = (bid - PB_WK) * 256 + tid;  src = Wv; dst = Wqkvb + (size_t)2560 * HID; }
  else if (bid < PB_WO) { i = (bid - PB_WV) * 256 + tid;  src = Wo; dst = Wob; }
  else {
    const int p = (bid - PB_WO) * 256 + tid;
    const int s = p >> 6, j = p & 63;
    float inv = expf(-(float)j * 0.14391156831212787f);
    float ang = (float)s * inv;
    float c, sn; sincosf(ang, &sn, &c);
    cs[p * 2 + 0] = c; cs[p * 2 + 1] = sn;
    return;
  }
  float4 v = ((const float4*)src)[i];
  ushort4 o;
  o.x = f2b(v.x); o.y = f2b(v.y); o.z = f2b(v.z); o.w = f2b(v.w);
  ((ushort4*)dst)[i] = o;
}

// ======================================================================
// 8-phase-style 256x256 GEMM (T2 swizzle + T3/T4 counted-vmcnt + T5)
// ======================================================================
#define MFMA_GRP(AV, BV, MO, NO)                                              \
  __builtin_amdgcn_s_setprio(1);                                              \
  _Pragma("unroll") for (int kk = 0; kk < 2; ++kk)                            \
  _Pragma("unroll") for (int mm = 0; mm < 4; ++mm)                            \
  _Pragma("unroll") for (int nn = 0; nn < 2; ++nn)                            \
    acc[(MO) + mm][(NO) + nn] = __builtin_amdgcn_mfma_f32_16x16x32_bf16(      \
        AV[kk][mm], BV[kk][nn], acc[(MO) + mm][(NO) + nn], 0, 0, 0);          \
  __builtin_amdgcn_s_setprio(0);

template <int OUT_BF16>
__global__ __launch_bounds__(512, 2) void k_gemm256(
    const u16* __restrict__ A, const u16* __restrict__ Bm, void* __restrict__ Cv,
    int M, int N, int K)
{
  __shared__ u16 AL[2][2][8192];   // 64 KB
  __shared__ u16 BL[2][2][8192];   // 64 KB
  const int tid = threadIdx.x;
  const int wave = tid >> 6, lane = tid & 63;
  const int l15 = lane & 15, l4 = lane >> 4;
  const int wr = wave >> 2, wc = wave & 3;
  const int gx = gridDim.x;
  const int nwg = gx * gridDim.y;
  int bid = blockIdx.y * gx + blockIdx.x;
  bid = (bid & 7) * (nwg >> 3) + (bid >> 3);
  const int col0 = (bid % gx) * 256, row0 = (bid / gx) * 256;

  int srcOff[2], dstD[2];
#pragma unroll
  for (int li = 0; li < 2; ++li) {
    const int D = (li * 512 + tid) * 16;
    const int off_p = D & 1023, si = D >> 10;
    const int off_l = off_p ^ (((off_p >> 9) & 1) << 5);
    const int R = si >> 1, C = si & 1;
    const int row = R * 16 + (off_l >> 6);
    const int colb = C * 64 + (off_l & 63);
    srcOff[li] = row * K + (colb >> 1);
    dstD[li] = D;
  }
  const int laneoff = (l15 * 64 + l4 * 16) ^ ((l15 >> 3) << 5);

  auto stage = [&](const u16* __restrict__ G, int grow0, int kb, u16* lds) {
#pragma unroll
    for (int li = 0; li < 2; ++li)
      gload_lds16(G + (size_t)grow0 * K + kb + srcOff[li],
                  (u16*)((char*)lds + dstD[li]));
  };

  f32x4 acc[8][4];
#pragma unroll
  for (int m = 0; m < 8; ++m)
#pragma unroll
    for (int n = 0; n < 4; ++n) acc[m][n] = f32x4{0.f, 0.f, 0.f, 0.f};

  const int nk = K >> 6;
  stage(A,  row0,       0,  &AL[0][0][0]);
  stage(A,  row0 + 128, 0,  &AL[0][1][0]);
  stage(Bm, col0,       0,  &BL[0][0][0]);
  stage(Bm, col0 + 128, 0,  &BL[0][1][0]);
  stage(A,  row0,       64, &AL[1][0][0]);
  stage(A,  row0 + 128, 64, &AL[1][1][0]);
  asm volatile("s_waitcnt vmcnt(4)" ::: "memory");
  SBAR();

  for (int t = 0; t < nk; ++t) {
    const int bi = t & 1;
    const bool sB = (t + 1 < nk);
    const bool sA = (t + 2 < nk);
    const char* Ab = (const char*)&AL[bi][wr][0];
    const char* Bb = (const char*)&BL[bi][wc >> 1][0] + (wc & 1) * 8192;
    bf16x8 a0[2][4], a1[2][4], b0[2][2], b1[2][2];
#pragma unroll
    for (int kk = 0; kk < 2; ++kk)
#pragma unroll
      for (int m = 0; m < 4; ++m)
        a0[kk][m] = *(const bf16x8*)(Ab + m * 2048 + kk * 1024 + laneoff);
#pragma unroll
    for (int kk = 0; kk < 2; ++kk)
#pragma unroll
      for (int n = 0; n < 2; ++n)
        b0[kk][n] = *(const bf16x8*)(Bb + n * 2048 + kk * 1024 + laneoff);
    if (sB) stage(Bm, col0, (t + 1) * 64, &BL[bi ^ 1][0][0]);
    SBAR();
    MFMA_GRP(a0, b0, 0, 0);
    SBAR();
#pragma unroll
    for (int kk = 0; kk < 2; ++kk)
#pragma unroll
      for (int m = 0; m < 4; ++m)
        a1[kk][m] = *(const bf16x8*)(Ab + (m + 4) * 2048 + kk * 1024 + laneoff);
    if (sB) stage(Bm, col0 + 128, (t + 1) * 64, &BL[bi ^ 1][1][0]);
    SBAR();
    MFMA_GRP(a1, b0, 4, 0);
    SBAR();
#pragma unroll
    for (int kk = 0; kk < 2; ++kk)
#pragma unroll
      for (int n = 0; n < 2; ++n)
        b1[kk][n] = *(const bf16x8*)(Bb + (n + 2) * 2048 + kk * 1024 + laneoff);
    if (sA) stage(A, row0, (t + 2) * 64, &AL[bi][0][0]);
    SBAR();
    MFMA_GRP(a1, b1, 4, 2);
    SBAR();
    if (sA) {
      stage(A, row0 + 128, (t + 2) * 64, &AL[bi][1][0]);
      asm volatile("s_waitcnt vmcnt(4)" ::: "memory");
    } else if (sB) {
      asm volatile("s_waitcnt vmcnt(0)" ::: "memory");
    }
    SBAR();
    MFMA_GRP(a0, b1, 0, 2);
    SBAR();
  }

#pragma unroll
  for (int m = 0; m < 8; ++m) {
    const int r = row0 + wr * 128 + m * 16 + l4 * 4;
#pragma unroll
    for (int n = 0; n < 4; ++n) {
      const int c = col0 + wc * 64 + n * 16 + l15;
#pragma unroll
      for (int j = 0; j < 4; ++j) {
        const float v = acc[m][n][j];
        if (OUT_BF16) ((u16*)Cv)[(size_t)(r + j) * N + c] = f2b(v);
        else          ((float*)Cv)[(size_t)(r + j) * N + c] = v;
      }
    }
  }
}

// C[M][N] = A[M][K] * B[N][K]^T, 128x128 tile, BK=32, 2-phase dbuf.
template <int OUT_BF16>
__global__ __launch_bounds__(256) void k_gemm_bt(
    const u16* __restrict__ A, const u16* __restrict__ Bm, void* __restrict__ Cv,
    int M, int N, int K)
{
  __shared__ u16 Al[2][128 * 32];
  __shared__ u16 Bl[2][128 * 32];
  const int tid = threadIdx.x;
  const int wave = tid >> 6, lane = tid & 63;
  const int l15 = lane & 15, l4 = lane >> 4;
  const int wr = wave >> 1, wc = wave & 1;
  const int row0 = blockIdx.y * 128, col0 = blockIdx.x * 128;

  f32x4 zero = {0.f, 0.f, 0.f, 0.f};
  f32x4 acc[4][4];
#pragma unroll
  for (int m = 0; m < 4; ++m)
#pragma unroll
    for (int n = 0; n < 4; ++n) acc[m][n] = zero;

  const int e0 = lane * 8;
  auto stage = [&](int buf, int kb) {
#pragma unroll
    for (int it = 0; it < 2; ++it) {
      const int chunk = it * 4 + wave;
      const int e = chunk * 512 + e0;
      const int r = e >> 5, c = e & 31;
      gload_lds16(A + (size_t)(row0 + r) * K + kb + c, &Al[buf][chunk * 512]);
      gload_lds16(Bm + (size_t)(col0 + r) * K + kb + c, &Bl[buf][chunk * 512]);
    }
  };

  stage(0, 0);
  asm volatile("s_waitcnt vmcnt(0)" ::: "memory");
  SBAR();
  int cur = 0;
  for (int kb = 0; kb < K; kb += 32) {
    if (kb + 32 < K) stage(cur ^ 1, kb + 32);   // issue early; lands under MFMA
    bf16x8 af[4], bfv[4];
#pragma unroll
    for (int m = 0; m < 4; ++m)
      af[m] = *(const bf16x8*)(&Al[cur][(wr * 64 + m * 16 + l15) * 32 + l4 * 8]);
#pragma unroll
    for (int n = 0; n < 4; ++n)
      bfv[n] = *(const bf16x8*)(&Bl[cur][(wc * 64 + n * 16 + l15) * 32 + l4 * 8]);
    __builtin_amdgcn_s_setprio(1);
#pragma unroll
    for (int m = 0; m < 4; ++m)
#pragma unroll
      for (int n = 0; n < 4; ++n)
        acc[m][n] = __builtin_amdgcn_mfma_f32_16x16x32_bf16(af[m], bfv[n], acc[m][n], 0, 0, 0);
    __builtin_amdgcn_s_setprio(0);
    asm volatile("s_waitcnt vmcnt(0)" ::: "memory");
    SBAR();
    cur ^= 1;
  }
#pragma unroll
  for (int m = 0; m < 4; ++m) {
    const int r = row0 + wr * 64 + m * 16 + l4 * 4;
#pragma unroll
    for (int n = 0; n < 4; ++n) {
      const int c = col0 + wc * 64 + n * 16 + l15;
#pragma unroll
      for (int j = 0; j < 4; ++j) {
        const float v = acc[m][n][j];
        if (OUT_BF16) ((u16*)Cv)[(size_t)(r + j) * N + c] = f2b(v);
        else          ((float*)Cv)[(size_t)(r + j) * N + c] = v;
      }
    }
  }
}

// ---- fused RoPE (Q pre-scaled by scale*log2e) + K RoPE + V transpose ----
// Vectorized: uint4 (8x u16) loads/stores for Q and K rope paths.
__global__ __launch_bounds__(256) void k_ropev(
    const u16* __restrict__ qkv, const float* __restrict__ cs,
    u16* __restrict__ Qr, u16* __restrict__ Kr, u16* __restrict__ Vt)
{
  const int blk = blockIdx.x;            // b*256 + (s>>3)
  const int b = blk >> 8, s0 = (blk & 255) << 3;
  const int tid = threadIdx.x;
  const float S2 = 0.08838834764831845f * 1.4426950408889634f;
  // Q: 8 s x 16 h x 8 j-octs = 1024 vec iters
#pragma unroll
  for (int p = tid; p < 1024; p += 256) {
    const int s = p >> 7, rem = p & 127, h = rem >> 3, j8 = (rem & 7) * 8;
    const int sg = s0 + s;
    const u16* src = qkv + (size_t)(b * S_LEN + sg) * QKV_N + h * 128 + j8;
    union { uint4 v; u16 u[8]; } lo, hi, olo, ohi;
    lo.v = *(const uint4*)(src);
    hi.v = *(const uint4*)(src + 64);
    const float* cp = cs + (size_t)(sg * 64 + j8) * 2;
#pragma unroll
    for (int k = 0; k < 8; ++k) {
      const float c = cp[k * 2], sn = cp[k * 2 + 1];
      const float x0 = b2f(lo.u[k]), x1 = b2f(hi.u[k]);
      olo.u[k] = f2b((x0 * c - x1 * sn) * S2);
      ohi.u[k] = f2b((x1 * c + x0 * sn) * S2);
    }
    u16* dst = Qr + ((size_t)(b * NHEADS + h) * S_LEN + sg) * HDIM + j8;
    *(uint4*)(dst) = olo.v;
    *(uint4*)(dst + 64) = ohi.v;
  }
  // K: 8 s x 4 h x 8 j-octs = 256 vec iters
  {
    const int p = tid;
    const int s = p >> 5, rem = p & 31, h = rem >> 3, j8 = (rem & 7) * 8;
    const int sg = s0 + s;
    const u16* src = qkv + (size_t)(b * S_LEN + sg) * QKV_N + 2048 + h * 128 + j8;
    union { uint4 v; u16 u[8]; } lo, hi, olo, ohi;
    lo.v = *(const uint4*)(src);
    hi.v = *(const uint4*)(src + 64);
    const float* cp = cs + (size_t)(sg * 64 + j8) * 2;
#pragma unroll
    for (int k = 0; k < 8; ++k) {
      const float c = cp[k * 2], sn = cp[k * 2 + 1];
      const float x0 = b2f(lo.u[k]), x1 = b2f(hi.u[k]);
      olo.u[k] = f2b(x0 * c - x1 * sn);
      ohi.u[k] = f2b(x1 * c + x0 * sn);
    }
    u16* dst = Kr + ((size_t)(b * NKVH + h) * S_LEN + sg) * HDIM + j8;
    *(uint4*)(dst) = olo.v;
    *(uint4*)(dst + 64) = ohi.v;
  }
  // V transpose: 512 (h,d) cols x 8 s -> one 16B store each
#pragma unroll
  for (int vi = 0; vi < 2; ++vi) {
    const int idx = vi * 256 + tid, h = idx >> 7, d = idx & 127;
    union { u16 u[8]; uint4 v; } bb;
#pragma unroll
    for (int s = 0; s < 8; ++s)
      bb.u[s] = qkv[(size_t)(b * S_LEN + s0 + s) * QKV_N + 2560 + idx];
    *(uint4*)(Vt + ((size_t)(b * NKVH + h) * HDIM + d) * S_LEN + s0) = bb.v;
  }
}

// ---- flash attention v6 (RESTORED — measured 79.0 us): swapped QK^T,
// ---- in-register P, PV via 16x16x16 MFMA, per-lane scalar softmax state ----
__device__ __forceinline__ void attn_qtile(
    int qt, int lastPhase,
    const u16* __restrict__ Q, const u16* __restrict__ Kg, const u16* __restrict__ Vg,
    u16* __restrict__ Out, int bh,
    u16* Kl0, u16* Kl1, u16* Vl0, u16* Vl1,
    const int (&ko)[4], const int (&vo)[4],
    int wave, int lane, int& cur)
{
  const int l15 = lane & 15, l4 = lane >> 4;
  const int b = bh >> 4, h = bh & 15;
  const int qw0 = qt * 64 + wave * 16;
  const u16* Qg = Q + ((size_t)bh * S_LEN + qw0) * HDIM;

  bf16x8 qf[4];
#pragma unroll
  for (int kc = 0; kc < 4; ++kc)
    qf[kc] = *(const bf16x8*)(Qg + l15 * HDIM + kc * 32 + l4 * 8);

  f32x4 zero = {0.f, 0.f, 0.f, 0.f};
  f32x4 oacc[8];
#pragma unroll
  for (int i = 0; i < 8; ++i) oacc[i] = zero;
  float m_r = -1e30f, l_p = 0.f;   // per-lane: full row state for q = qw0 + l15

  const int nt = qt + 1;
  const int qg = qw0 + l15;

  for (int t = 0; t < nt; ++t) {
    const int kt = t * 64;
    u16* Vb = cur ? Vl1 : Vl0;
#pragma unroll
    for (int it = 0; it < 4; ++it)
      gload_lds16(Vg + (size_t)vo[it] + kt, Vb + (it * 4 + wave) * 512);
    const int hasNext = (t + 1 < nt) || (!lastPhase);
    const int ktn = (t + 1 < nt) ? kt + 64 : 0;
    u16* Kn = cur ? Kl0 : Kl1;
    if (hasNext) {
#pragma unroll
      for (int it = 0; it < 4; ++it)
        gload_lds16(Kg + (size_t)ktn * HDIM + ko[it], Kn + (it * 4 + wave) * 512);
      asm volatile("s_waitcnt vmcnt(8)" ::: "memory");
    } else {
      asm volatile("s_waitcnt vmcnt(4)" ::: "memory");
    }
    __builtin_amdgcn_sched_barrier(0);
    __builtin_amdgcn_s_barrier();
    __builtin_amdgcn_sched_barrier(0);

    const char* Kb = (const char*)(cur ? Kl1 : Kl0);
    // ---- S^T = K Q^T : lane owns q=l15, k = 16n + 4*l4 + j ----
    f32x4 s[4];
#pragma unroll
    for (int n = 0; n < 4; ++n) s[n] = zero;
    __builtin_amdgcn_s_setprio(1);
#pragma unroll
    for (int n = 0; n < 4; ++n) {
      const int row = n * 16 + l15;
#pragma unroll
      for (int kc = 0; kc < 4; ++kc) {
        const int ab = (row * 256 + kc * 64 + l4 * 16) ^ ((row & 7) << 4);
        bf16x8 kf = *(const bf16x8*)(Kb + ab);
        s[n] = __builtin_amdgcn_mfma_f32_16x16x32_bf16(kf, qf[kc], s[n], 0, 0, 0);
      }
    }
    __builtin_amdgcn_s_setprio(0);
    // ---- (rare) causal mask + per-lane max over owned k ----
    float sv[4][4];
    if (kt + 63 > qw0) {
#pragma unroll
      for (int n = 0; n < 4; ++n)
#pragma unroll
        for (int j = 0; j < 4; ++j) {
          float x = s[n][j];
          if (kt + n * 16 + l4 * 4 + j > qg) x = -1e30f;
          sv[n][j] = x;
        }
    } else {
#pragma unroll
      for (int n = 0; n < 4; ++n)
#pragma unroll
        for (int j = 0; j < 4; ++j) sv[n][j] = s[n][j];
    }
    float pm = sv[0][0];
#pragma unroll
    for (int n = 0; n < 4; ++n)
#pragma unroll
      for (int j = 0; j < 4; ++j) pm = fmaxf(pm, sv[n][j]);
    // ---- defer-max: rescale only when the lane's partial max jumps ----
    if (!__all(pm <= m_r + 11.5416f)) {
      float pf = fmaxf(pm, __shfl_xor(pm, 16, 64));
      pf = fmaxf(pf, __shfl_xor(pf, 32, 64));          // full row max (quad)
      const float mn = fmaxf(m_r, pf);
      const float sc = exp2f(m_r - mn);
      m_r = mn;
      l_p *= sc;
      float scq[4];
#pragma unroll
      for (int j = 0; j < 4; ++j) scq[j] = __shfl(sc, l4 * 4 + j, 64);
#pragma unroll
      for (int nd = 0; nd < 8; ++nd)
#pragma unroll
        for (int j = 0; j < 4; ++j) oacc[nd][j] *= scq[j];
    }
    // ---- P = exp2(sv - m), pack to bf16 pairs in-register (A-frags) ----
    union { unsigned u[2]; s16x4 v; } a[4];
#pragma unroll
    for (int n = 0; n < 4; ++n) {
      const float p0 = exp2f(sv[n][0] - m_r);
      const float p1 = exp2f(sv[n][1] - m_r);
      const float p2 = exp2f(sv[n][2] - m_r);
      const float p3 = exp2f(sv[n][3] - m_r);
      l_p += (p0 + p1) + (p2 + p3);
      a[n].u[0] = cvtpk(p0, p1);
      a[n].u[1] = cvtpk(p2, p3);
    }
    // ---- V(t) ready ----
    if (hasNext) asm volatile("s_waitcnt vmcnt(4)" ::: "memory");
    else         asm volatile("s_waitcnt vmcnt(0)" ::: "memory");
    __builtin_amdgcn_sched_barrier(0);
    __builtin_amdgcn_s_barrier();
    __builtin_amdgcn_sched_barrier(0);
    // ---- O += P V : 16x16x16 MFMA, A direct from registers ----
    __builtin_amdgcn_s_setprio(1);
#pragma unroll
    for (int nd = 0; nd < 8; ++nd) {
      const int d = nd * 16 + l15;
      const int rowb = d * 128, swz = (d & 7) << 4;
#pragma unroll
      for (int n = 0; n < 4; ++n) {
        const int ab = (rowb + n * 32 + l4 * 8) ^ swz;
        s16x4 vf = *(const s16x4*)((const char*)Vb + ab);
        oacc[nd] = mfma16(a[n].v, vf, oacc[nd]);
      }
    }
    __builtin_amdgcn_s_setprio(0);
    cur ^= 1;
  }

  // ---- epilogue: finish l reduction, fetch per-row l, normalize, store ----
  l_p += __shfl_xor(l_p, 16, 64);
  l_p += __shfl_xor(l_p, 32, 64);
  float il[4];
#pragma unroll
  for (int j = 0; j < 4; ++j) il[j] = 1.f / __shfl(l_p, l4 * 4 + j, 64);
  const size_t obase = ((size_t)b * S_LEN + qw0 + l4 * 4) * HID + h * HDIM;
#pragma unroll
  for (int nd = 0; nd < 8; ++nd)
#pragma unroll
    for (int j = 0; j < 4; ++j)
      Out[obase + (size_t)j * HID + nd * 16 + l15] = f2b(oacc[nd][j] * il[j]);
}

__global__ __launch_bounds__(256) void k_attn(
    const u16* __restrict__ Q, const u16* __restrict__ Kr,
    const u16* __restrict__ Vt, u16* __restrict__ Out)
{
  __shared__ u16 Kl[2][64 * 128];   // 32 KB dbuf, XOR ^((kv&7)<<4)
  __shared__ u16 Vl[2][128 * 64];   // 32 KB dbuf, XOR ^((d&7)<<4)
  const int tid = threadIdx.x;
  const int wave = tid >> 6, lane = tid & 63;
  const int bh = blockIdx.x;              // XCD = bh%8: KV L2 locality
  const int pairi = blockIdx.y;           // pair (31-pairi, pairi): 33 tiles/block
  const int b = bh >> 4, h = bh & 15;
  const int kvh = h >> 2;

  const u16* Kg = Kr + (size_t)(b * NKVH + kvh) * S_LEN * HDIM;
  const u16* Vg = Vt + (size_t)(b * NKVH + kvh) * HDIM * S_LEN;

  int ko[4], vo[4];
#pragma unroll
  for (int it = 0; it < 4; ++it) {
    const int c = it * 4 + wave;
    const int L = c * 1024 + lane * 16;
    const int r = L >> 8;  const int w2 = (L & 255) ^ ((r & 7) << 4);
    ko[it] = r * HDIM + (w2 >> 1);
    const int d = L >> 7;  const int wv = (L & 127) ^ ((d & 7) << 4);
    vo[it] = d * S_LEN + (wv >> 1);
  }
#pragma unroll
  for (int it = 0; it < 4; ++it)
    gload_lds16(Kg + ko[it], &Kl[0][(it * 4 + wave) * 512]);

  int cur = 0;
  attn_qtile(31 - pairi, 0, Q, Kg, Vg, Out, bh, &Kl[0][0], &Kl[1][0],
             &Vl[0][0], &Vl[1][0], ko, vo, wave, lane, cur);
  attn_qtile(pairi,      1, Q, Kg, Vg, Out, bh, &Kl[0][0], &Kl[1][0],
             &Vl[0][0], &Vl[1][0], ko, vo, wave, lane, cur);
}

extern "C" void kernel_launch(void* const* d_in, const int* in_sizes, int n_in,
                              void* d_out, int out_size, void* d_ws, size_t ws_size,
                              hipStream_t stream)
{
  const float* x  = (const float*)d_in[0];
  const float* Wq = (const float*)d_in[2];
  const float* Wk = (const float*)d_in[3];
  const float* Wv = (const float*)d_in[4];
  const float* Wo = (const float*)d_in[5];
  float* out = (float*)d_out;

  u16* xb    = (u16*)d_ws;
  u16* Wqkvb = xb    + (size_t)MROWS * HID;
  u16* Wob   = Wqkvb + (size_t)QKV_N * HID;
  u16* qkv   = Wob   + (size_t)HID * HID;
  u16* Qr    = qkv   + (size_t)MROWS * QKV_N;
  u16* Kr    = Qr    + (size_t)BB * NHEADS * S_LEN * HDIM;
  u16* Vt    = Kr    + (size_t)BB * NKVH * S_LEN * HDIM;
  u16* attn  = Vt    + (size_t)BB * NKVH * S_LEN * HDIM;
  float* cs  = (float*)(attn + (size_t)MROWS * HID);

  k_prep<<<dim3(PB_CS), 256, 0, stream>>>(x, Wq, Wk, Wv, Wo, xb, Wqkvb, Wob, cs);
  k_gemm256<1><<<dim3(QKV_N / 256, MROWS / 256), 512, 0, stream>>>(xb, Wqkvb, qkv, MROWS, QKV_N, HID);
  k_ropev<<<dim3(BB * 256), 256, 0, stream>>>(qkv, cs, Qr, Kr, Vt);
  k_attn<<<dim3(BB * NHEADS, 16), 256, 0, stream>>>(Qr, Kr, Vt, attn);
  k_gemm_bt<0><<<dim3(HID / 128, MROWS / 128), 256, 0, stream>>>(attn, Wob, out, MROWS, HID, HID);
}